// Round 1
// baseline (105.627 us; speedup 1.0000x reference)
//
#include <hip/hip_runtime.h>

typedef unsigned int u32;
typedef unsigned short u16;
typedef _Float16 f16;
typedef f16 f16x8 __attribute__((ext_vector_type(8)));
typedef float f32x4 __attribute__((ext_vector_type(4)));

#define SH1 72   // h1buf row stride in f16 (144 B = 9*16B: keeps frag reads 16B-aligned, 2-way banks)

// One WAVE per row i (grid 1024 x 64). Single-wave workgroup => every
// __syncthreads() degenerates to a waitcnt (no cross-wave barrier stalls),
// compaction is ballot+popc (no LDS atomics), and all 64 lanes are busy in
// every phase (the old 256-thread block idled 75-98% of lanes in the MLP head
// and paid ~15 multi-wave barriers).
//  Phase 1: 16-iter coalesced scan, ballot-prefix compaction of actives
//           (precomputes conv1 features x0..x4 at scan time).
//  Phase 2: conv1 in registers (channel = lane, w1 row in 6 VGPRs) ->
//           h1 f16 in LDS -> conv2 via v_mfma_f32_16x16x32_f16, wave owns all
//           8 N-tiles (bfrag = 64 VGPRs loaded once) -> masked max epilogue.
//  Phase 3: MLP head fully lane-parallel: fc1 1 out/lane, fc2 2 out/lane,
//           fc3 1 out/lane, fc4 split-K over 16-lane groups + shfl reduce.
__global__ __launch_bounds__(64) void NetworkAction_86131274154571_kernel(
    const float* __restrict__ s,    const float* __restrict__ g,
    const float* __restrict__ w1g,  const float* __restrict__ b1g,
    const float* __restrict__ w2g,  const float* __restrict__ b2g,
    const float* __restrict__ fc1w, const float* __restrict__ fc1b,
    const float* __restrict__ fc2w, const float* __restrict__ fc2b,
    const float* __restrict__ fc3w, const float* __restrict__ fc3b,
    const float* __restrict__ fc4w, const float* __restrict__ fc4b,
    float2* __restrict__ out)
{
    __shared__ float4 actx[1024];     // (x0,x1,x2,x3) = si - sj for actives
    __shared__ float  actf[1024];     // x4 = diagonal flag
    __shared__ f16    h1buf[16][SH1]; // one 16-pair group of conv1 outputs
    __shared__ float  feat[132];      // [0..127] pooled, [128..131] sg|v
    __shared__ float  z1[64];
    __shared__ float  z2[128];
    __shared__ float  z3[64];
    __shared__ float  kk[4];

    const int lane = threadIdx.x;     // 0..63
    const int i    = blockIdx.x;
    const int ncol = lane & 15;
    const int kq   = lane >> 4;       // 0..3

    const float4 si = ((const float4*)s)[i];   // wave-uniform

    // ---- conv1 weights for channel `lane` -> registers (loaded once) ----
    const float* wp1 = w1g + lane * 5;
    const float w10 = wp1[0], w11 = wp1[1], w12 = wp1[2], w13 = wp1[3], w14 = wp1[4];
    const float b1r = b1g[lane];

    // ---- conv2 B-fragments: this wave owns ALL 8 N-tiles (128 channels) ----
    // B[k][n] = w2[n][k]; lane: n = tile*16 + ncol, k = kq*8 + j (+ t*32)
    f16x8 bfrag[8][2];
    float b2r[8];
    #pragma unroll
    for (int tile = 0; tile < 8; ++tile) {
        const int n = tile * 16 + ncol;
        b2r[tile] = b2g[n];
        #pragma unroll
        for (int t = 0; t < 2; ++t) {
            const float* wp = w2g + n * 64 + t * 32 + kq * 8;
            float4 lo = ((const float4*)wp)[0];
            float4 hi = ((const float4*)wp)[1];
            f16x8 b;
            b[0] = (f16)lo.x; b[1] = (f16)lo.y; b[2] = (f16)lo.z; b[3] = (f16)lo.w;
            b[4] = (f16)hi.x; b[5] = (f16)hi.y; b[6] = (f16)hi.z; b[7] = (f16)hi.w;
            bfrag[tile][t] = b;
        }
    }

    // ---- Phase 1: scan + ballot compaction (no atomics) ----
    int cnt = 0;
    #pragma unroll
    for (int it = 0; it < 16; ++it) {
        const int j = it * 64 + lane;              // coalesced
        float4 sj = ((const float4*)s)[j];
        float dx = si.x - sj.x, dy = si.y - sj.y;
        bool act = (dx * dx + dy * dy) < 0.25f;
        unsigned long long m = __ballot(act);
        if (act) {
            int pos = cnt + (int)__popcll(m & ((1ull << lane) - 1ull));
            actx[pos] = make_float4(dx, dy, si.z - sj.z, si.w - sj.w);
            actf[pos] = (j == i) ? 1.0f : 0.0f;
        }
        cnt += (int)__popcll(m);
    }
    const int n_act = cnt;                         // >=1 (diagonal)
    __syncthreads();                               // single wave: just a waitcnt

    float mt[8];
    #pragma unroll
    for (int t = 0; t < 8; ++t) mt[t] = 0.0f;

    // ---- Phase 2: groups of 16 pairs ----
    for (int gbase = 0; gbase < n_act; gbase += 16) {
        // conv1: channel = lane, loop pairs (branches are wave-uniform)
        #pragma unroll
        for (int p = 0; p < 16; ++p) {
            if (gbase + p < n_act) {
                const float4 x  = actx[gbase + p];     // LDS broadcast
                const float  x4 = actf[gbase + p];
                float h = b1r;
                h = fmaf(w10, x.x, h); h = fmaf(w11, x.y, h);
                h = fmaf(w12, x.z, h); h = fmaf(w13, x.w, h);
                h = fmaf(w14, x4,  h);
                h1buf[p][lane] = (f16)fmaxf(h, 0.0f); // 2B/lane: 2-way banks, free
            }
        }
        __syncthreads();

        // conv2 MFMA: A-frags shared by all 8 tiles
        f16x8 afr[2];
        #pragma unroll
        for (int t = 0; t < 2; ++t)
            afr[t] = *(const f16x8*)&h1buf[ncol][t * 32 + kq * 8];  // 16B-aligned

        #pragma unroll
        for (int tile = 0; tile < 8; ++tile) {
            f32x4 acc = {0.0f, 0.0f, 0.0f, 0.0f};
            acc = __builtin_amdgcn_mfma_f32_16x16x32_f16(afr[0], bfrag[tile][0], acc, 0, 0, 0);
            acc = __builtin_amdgcn_mfma_f32_16x16x32_f16(afr[1], bfrag[tile][1], acc, 0, 0, 0);
            // D: pair row = kq*4 + r, channel col = ncol; mask pad rows
            #pragma unroll
            for (int r = 0; r < 4; ++r) {
                const bool valid = (gbase + kq * 4 + r) < n_act;
                const float v = acc[r] + b2r[tile];
                mt[tile] = valid ? fmaxf(mt[tile], v) : mt[tile];
            }
        }
        __syncthreads();   // h1buf reused next group
    }

    // reduce across the 4 row-quads holding the same channel column
    #pragma unroll
    for (int tile = 0; tile < 8; ++tile) {
        float m = mt[tile];
        m = fmaxf(m, __shfl_xor(m, 16));
        m = fmaxf(m, __shfl_xor(m, 32));
        if (lane < 16) feat[tile * 16 + lane] = m;
    }
    if (lane == 0) {
        float2 gi = ((const float2*)g)[i];
        feat[128] = si.x - gi.x;
        feat[129] = si.y - gi.y;
        feat[130] = si.z;
        feat[131] = si.w;
    }
    __syncthreads();

    // ---- Phase 3: MLP head, all 64 lanes busy every layer ----
    // fc1: out = lane, K=132
    {
        float a0 = fc1b[lane], a1 = 0.f, a2 = 0.f, a3 = 0.f;
        const float4* wv = (const float4*)(fc1w + lane * 132);
        #pragma unroll
        for (int q = 0; q < 33; ++q) {
            float4 u = wv[q];
            const int k = q * 4;
            float* a = (q & 3) == 0 ? &a0 : (q & 3) == 1 ? &a1 : (q & 3) == 2 ? &a2 : &a3;
            *a = fmaf(u.x, feat[k + 0], *a);
            *a = fmaf(u.y, feat[k + 1], *a);
            *a = fmaf(u.z, feat[k + 2], *a);
            *a = fmaf(u.w, feat[k + 3], *a);
        }
        z1[lane] = fmaxf((a0 + a1) + (a2 + a3), 0.0f);
    }
    __syncthreads();

    // fc2: out = lane and lane+64, K=64
    {
        float aA0 = fc2b[lane],      aA1 = 0.f;
        float aB0 = fc2b[lane + 64], aB1 = 0.f;
        const float4* wvA = (const float4*)(fc2w + lane * 64);
        const float4* wvB = (const float4*)(fc2w + (lane + 64) * 64);
        #pragma unroll
        for (int q = 0; q < 16; ++q) {
            float4 uA = wvA[q];
            float4 uB = wvB[q];
            const int k = q * 4;
            const float f0 = z1[k + 0], f1 = z1[k + 1], f2 = z1[k + 2], f3 = z1[k + 3];
            if (q & 1) {
                aA1 = fmaf(uA.x, f0, aA1); aA1 = fmaf(uA.y, f1, aA1);
                aA1 = fmaf(uA.z, f2, aA1); aA1 = fmaf(uA.w, f3, aA1);
                aB1 = fmaf(uB.x, f0, aB1); aB1 = fmaf(uB.y, f1, aB1);
                aB1 = fmaf(uB.z, f2, aB1); aB1 = fmaf(uB.w, f3, aB1);
            } else {
                aA0 = fmaf(uA.x, f0, aA0); aA0 = fmaf(uA.y, f1, aA0);
                aA0 = fmaf(uA.z, f2, aA0); aA0 = fmaf(uA.w, f3, aA0);
                aB0 = fmaf(uB.x, f0, aB0); aB0 = fmaf(uB.y, f1, aB0);
                aB0 = fmaf(uB.z, f2, aB0); aB0 = fmaf(uB.w, f3, aB0);
            }
        }
        z2[lane]      = fmaxf(aA0 + aA1, 0.0f);
        z2[lane + 64] = fmaxf(aB0 + aB1, 0.0f);
    }
    __syncthreads();

    // fc3: out = lane, K=128
    {
        float a0 = fc3b[lane], a1 = 0.f, a2 = 0.f, a3 = 0.f;
        const float4* wv = (const float4*)(fc3w + lane * 128);
        #pragma unroll
        for (int q = 0; q < 32; ++q) {
            float4 u = wv[q];
            const int k = q * 4;
            float* a = (q & 3) == 0 ? &a0 : (q & 3) == 1 ? &a1 : (q & 3) == 2 ? &a2 : &a3;
            *a = fmaf(u.x, z2[k + 0], *a);
            *a = fmaf(u.y, z2[k + 1], *a);
            *a = fmaf(u.z, z2[k + 2], *a);
            *a = fmaf(u.w, z2[k + 3], *a);
        }
        z3[lane] = fmaxf((a0 + a1) + (a2 + a3), 0.0f);
    }
    __syncthreads();

    // fc4: 4 outputs, split-K over 16-lane groups; q = lane>>4, ks = lane&15
    {
        const int q  = lane >> 4;
        const int ks = lane & 15;
        float4 u = ((const float4*)(fc4w + q * 64))[ks];
        float part = u.x * z3[ks * 4 + 0] + u.y * z3[ks * 4 + 1]
                   + u.z * z3[ks * 4 + 2] + u.w * z3[ks * 4 + 3];
        part += __shfl_xor(part, 1);
        part += __shfl_xor(part, 2);
        part += __shfl_xor(part, 4);
        part += __shfl_xor(part, 8);
        if (ks == 0)
            kk[q] = 2.0f / (1.0f + expf(-(part + fc4b[q]))) - 1.0f;
    }
    __syncthreads();

    if (lane == 0) {
        float ax = -(kk[0] * feat[128] + kk[1] * feat[130]);
        float ay = -(kk[2] * feat[129] + kk[3] * feat[131]);
        out[i] = make_float2(ax, ay);
    }
}

extern "C" void kernel_launch(void* const* d_in, const int* in_sizes, int n_in,
                              void* d_out, int out_size, void* d_ws, size_t ws_size,
                              hipStream_t stream) {
    const float* s    = (const float*)d_in[0];
    const float* g    = (const float*)d_in[1];
    const float* c1w  = (const float*)d_in[2];
    const float* c1b  = (const float*)d_in[3];
    const float* c2w  = (const float*)d_in[4];
    const float* c2b  = (const float*)d_in[5];
    const float* fc1w = (const float*)d_in[6];
    const float* fc1b = (const float*)d_in[7];
    const float* fc2w = (const float*)d_in[8];
    const float* fc2b = (const float*)d_in[9];
    const float* fc3w = (const float*)d_in[10];
    const float* fc3b = (const float*)d_in[11];
    const float* fc4w = (const float*)d_in[12];
    const float* fc4b = (const float*)d_in[13];

    float2* out = (float2*)d_out;

    NetworkAction_86131274154571_kernel<<<1024, 64, 0, stream>>>(
        s, g, c1w, c1b, c2w, c2b, fc1w, fc1b, fc2w, fc2b,
        fc3w, fc3b, fc4w, fc4b, out);
}

// Round 2
// 104.392 us; speedup vs baseline: 1.0118x; 1.0118x over previous
//
#include <hip/hip_runtime.h>

typedef unsigned int u32;
typedef unsigned short u16;
typedef _Float16 f16;
typedef f16 f16x8 __attribute__((ext_vector_type(8)));
typedef float f32x4 __attribute__((ext_vector_type(4)));

#define NTH 256
#define SH1 72   // h1 row stride in f16 (144 B = 9*16 B: 16B-aligned frags, no 128B bank wrap)
#define SW2 72   // staged-w2 row stride in f16 (same property)

// 256 threads = 4 waves per row i; each wave INDEPENDENTLY owns a quarter of
// the candidate scan. Max-pool is order-independent over a disjoint partition,
// so waves never share conv work:
//   - per-wave ballot compaction into a private actx region (no atomics)
//   - per-wave conv1 (channel = lane) -> private h1 tile -> conv2 over all 8
//     N-tiles via v_mfma_f32_16x16x32_f16 (B-frags from f16 w2 staged in LDS;
//     no 64 persistent VGPRs) -> per-wave partial max mt[8]
// Only TWO block barriers: (1) after w2 staging + scan, (2) before the head.
// Head (fc1..fc4 + gains) runs on wave 0 alone with in-wave s_waitcnt instead
// of block barriers; waves 1-3 retire at barrier 2.
// Rationale vs round 1 (1 wave/block, 105.6us): that shape held 1 wave/SIMD
// chip-wide -- zero latency hiding. This keeps round-1's barrier-freedom in
// the hot phases but restores 12 waves/CU residency (LDS-bound 3 blocks/CU).
__global__ __launch_bounds__(NTH) void NetworkAction_86131274154571_kernel(
    const float* __restrict__ s,    const float* __restrict__ g,
    const float* __restrict__ w1g,  const float* __restrict__ b1g,
    const float* __restrict__ w2g,  const float* __restrict__ b2g,
    const float* __restrict__ fc1w, const float* __restrict__ fc1b,
    const float* __restrict__ fc2w, const float* __restrict__ fc2b,
    const float* __restrict__ fc3w, const float* __restrict__ fc3b,
    const float* __restrict__ fc4w, const float* __restrict__ fc4b,
    float2* __restrict__ out)
{
    __shared__ float4 actx[1024];        // 4 disjoint 256-slot per-wave regions
    __shared__ f16    w2s[128][SW2];     // w2 as f16, row n = output channel
    __shared__ f16    h1all[4][16][SH1]; // per-wave conv1 tile
    __shared__ float  pmax[4][128];      // per-wave partial channel maxes
    __shared__ int    diagslot[4];
    __shared__ float  feat[132];
    __shared__ float  z1[64];
    __shared__ float  z2[128];
    __shared__ float  z3[64];

    const int tid  = threadIdx.x;
    const int lane = tid & 63;
    const int wave = tid >> 6;
    const int i    = blockIdx.x;
    const int ncol = lane & 15;
    const int kq   = lane >> 4;          // 0..3

    const float4 si = ((const float4*)s)[i];   // uniform

    if (lane == 0) diagslot[wave] = -1;

    // ---- stage w2 -> f16 LDS (one-time, 256 threads: row = tid>>1, half = tid&1) ----
    {
        const int n = tid >> 1, h = tid & 1;
        const float4* wp = (const float4*)(w2g + n * 64 + h * 32);
        #pragma unroll
        for (int q = 0; q < 8; q += 2) {
            float4 u0 = wp[q], u1 = wp[q + 1];
            f16x8 b;
            b[0] = (f16)u0.x; b[1] = (f16)u0.y; b[2] = (f16)u0.z; b[3] = (f16)u0.w;
            b[4] = (f16)u1.x; b[5] = (f16)u1.y; b[6] = (f16)u1.z; b[7] = (f16)u1.w;
            *(f16x8*)&w2s[n][h * 32 + q * 4] = b;   // 16B-aligned
        }
    }

    // ---- conv1 weights for channel `lane` + conv2 bias ----
    const float* wp1 = w1g + lane * 5;
    const float w10 = wp1[0], w11 = wp1[1], w12 = wp1[2], w13 = wp1[3], w14 = wp1[4];
    const float b1r = b1g[lane];
    float b2r[8];
    #pragma unroll
    for (int t = 0; t < 8; ++t) b2r[t] = b2g[t * 16 + ncol];

    // ---- Phase 1: per-wave scan of 256 candidates + ballot compaction ----
    int cnt = 0;
    const int jbase = wave * 256;
    #pragma unroll
    for (int it = 0; it < 4; ++it) {
        const int j = jbase + it * 64 + lane;          // coalesced
        float4 sj = ((const float4*)s)[j];
        float dx = si.x - sj.x, dy = si.y - sj.y;
        bool act = (dx * dx + dy * dy) < 0.25f;
        unsigned long long m = __ballot(act);
        if (act) {
            int pos = cnt + (int)__popcll(m & ((1ull << lane) - 1ull));
            actx[jbase + pos] = make_float4(dx, dy, si.z - sj.z, si.w - sj.w);
            if (j == i) diagslot[wave] = pos;
        }
        cnt += (int)__popcll(m);
    }
    __syncthreads();   // barrier 1: w2s visible to all waves; own actx ordered

    const int dslot = diagslot[wave];                 // wave-uniform
    const float4* actw = &actx[jbase];
    f16 (*h1buf)[SH1] = h1all[wave];

    float mt[8];
    #pragma unroll
    for (int t = 0; t < 8; ++t) mt[t] = 0.0f;

    // ---- Phase 2: per-wave groups of 16 pairs (NO block barriers) ----
    for (int gbase = 0; gbase < cnt; gbase += 16) {
        #pragma unroll
        for (int p = 0; p < 16; ++p) {
            if (gbase + p < cnt) {                     // wave-uniform branch
                const float4 x  = actw[gbase + p];     // LDS broadcast
                const float  x4 = (gbase + p == dslot) ? 1.0f : 0.0f;
                float h = b1r;
                h = fmaf(w10, x.x, h); h = fmaf(w11, x.y, h);
                h = fmaf(w12, x.z, h); h = fmaf(w13, x.w, h);
                h = fmaf(w14, x4,  h);
                h1buf[p][lane] = (f16)fmaxf(h, 0.0f);  // 2B/lane: 2-way banks, free
            }
        }
        // in-wave ordering of h1 writes vs frag reads (LDS pipe is in-order,
        // this pins the compiler's schedule)
        asm volatile("s_waitcnt lgkmcnt(0)" ::: "memory");

        f16x8 afr0 = *(const f16x8*)&h1buf[ncol][kq * 8];        // 16B-aligned
        f16x8 afr1 = *(const f16x8*)&h1buf[ncol][32 + kq * 8];

        #pragma unroll
        for (int tile = 0; tile < 8; ++tile) {
            const int n = tile * 16 + ncol;
            f16x8 b0 = *(const f16x8*)&w2s[n][kq * 8];
            f16x8 b1 = *(const f16x8*)&w2s[n][32 + kq * 8];
            f32x4 acc = {0.0f, 0.0f, 0.0f, 0.0f};
            acc = __builtin_amdgcn_mfma_f32_16x16x32_f16(afr0, b0, acc, 0, 0, 0);
            acc = __builtin_amdgcn_mfma_f32_16x16x32_f16(afr1, b1, acc, 0, 0, 0);
            // D: pair row = kq*4 + r, channel col = ncol; mask pad rows
            #pragma unroll
            for (int r = 0; r < 4; ++r) {
                const bool valid = (gbase + kq * 4 + r) < cnt;
                const float v = acc[r] + b2r[tile];
                mt[tile] = valid ? fmaxf(mt[tile], v) : mt[tile];
            }
        }
    }

    // per-wave reduce across the 4 row-quads sharing a channel column
    #pragma unroll
    for (int tile = 0; tile < 8; ++tile) {
        float m = mt[tile];
        m = fmaxf(m, __shfl_xor(m, 16));
        m = fmaxf(m, __shfl_xor(m, 32));
        if (lane < 16) pmax[wave][tile * 16 + lane] = m;
    }
    __syncthreads();   // barrier 2: pmax visible
    if (wave != 0) return;

    // ---- wave-0-only head: combine partials + MLP, in-wave waitcnts only ----
    {
        float m0 = fmaxf(fmaxf(pmax[0][lane],      pmax[1][lane]),
                         fmaxf(pmax[2][lane],      pmax[3][lane]));
        float m1 = fmaxf(fmaxf(pmax[0][lane + 64], pmax[1][lane + 64]),
                         fmaxf(pmax[2][lane + 64], pmax[3][lane + 64]));
        feat[lane]      = m0;
        feat[lane + 64] = m1;
    }
    const float2 gi = ((const float2*)g)[i];
    const float sgx = si.x - gi.x, sgy = si.y - gi.y;
    if (lane == 0) {
        feat[128] = sgx; feat[129] = sgy; feat[130] = si.z; feat[131] = si.w;
    }
    asm volatile("s_waitcnt lgkmcnt(0)" ::: "memory");

    // fc1: out = lane, K=132
    {
        float a0 = fc1b[lane], a1 = 0.f, a2 = 0.f, a3 = 0.f;
        const float4* wv = (const float4*)(fc1w + lane * 132);
        #pragma unroll
        for (int q = 0; q < 33; ++q) {
            float4 u = wv[q];
            const int k = q * 4;
            float* a = (q & 3) == 0 ? &a0 : (q & 3) == 1 ? &a1 : (q & 3) == 2 ? &a2 : &a3;
            *a = fmaf(u.x, feat[k + 0], *a);
            *a = fmaf(u.y, feat[k + 1], *a);
            *a = fmaf(u.z, feat[k + 2], *a);
            *a = fmaf(u.w, feat[k + 3], *a);
        }
        z1[lane] = fmaxf((a0 + a1) + (a2 + a3), 0.0f);
    }
    asm volatile("s_waitcnt lgkmcnt(0)" ::: "memory");

    // fc2: out = lane and lane+64, K=64
    {
        float aA0 = fc2b[lane],      aA1 = 0.f;
        float aB0 = fc2b[lane + 64], aB1 = 0.f;
        const float4* wvA = (const float4*)(fc2w + lane * 64);
        const float4* wvB = (const float4*)(fc2w + (lane + 64) * 64);
        #pragma unroll
        for (int q = 0; q < 16; ++q) {
            float4 uA = wvA[q];
            float4 uB = wvB[q];
            const int k = q * 4;
            const float f0 = z1[k + 0], f1 = z1[k + 1], f2 = z1[k + 2], f3 = z1[k + 3];
            if (q & 1) {
                aA1 = fmaf(uA.x, f0, aA1); aA1 = fmaf(uA.y, f1, aA1);
                aA1 = fmaf(uA.z, f2, aA1); aA1 = fmaf(uA.w, f3, aA1);
                aB1 = fmaf(uB.x, f0, aB1); aB1 = fmaf(uB.y, f1, aB1);
                aB1 = fmaf(uB.z, f2, aB1); aB1 = fmaf(uB.w, f3, aB1);
            } else {
                aA0 = fmaf(uA.x, f0, aA0); aA0 = fmaf(uA.y, f1, aA0);
                aA0 = fmaf(uA.z, f2, aA0); aA0 = fmaf(uA.w, f3, aA0);
                aB0 = fmaf(uB.x, f0, aB0); aB0 = fmaf(uB.y, f1, aB0);
                aB0 = fmaf(uB.z, f2, aB0); aB0 = fmaf(uB.w, f3, aB0);
            }
        }
        z2[lane]      = fmaxf(aA0 + aA1, 0.0f);
        z2[lane + 64] = fmaxf(aB0 + aB1, 0.0f);
    }
    asm volatile("s_waitcnt lgkmcnt(0)" ::: "memory");

    // fc3: out = lane, K=128
    {
        float a0 = fc3b[lane], a1 = 0.f, a2 = 0.f, a3 = 0.f;
        const float4* wv = (const float4*)(fc3w + lane * 128);
        #pragma unroll
        for (int q = 0; q < 32; ++q) {
            float4 u = wv[q];
            const int k = q * 4;
            float* a = (q & 3) == 0 ? &a0 : (q & 3) == 1 ? &a1 : (q & 3) == 2 ? &a2 : &a3;
            *a = fmaf(u.x, z2[k + 0], *a);
            *a = fmaf(u.y, z2[k + 1], *a);
            *a = fmaf(u.z, z2[k + 2], *a);
            *a = fmaf(u.w, z2[k + 3], *a);
        }
        z3[lane] = fmaxf((a0 + a1) + (a2 + a3), 0.0f);
    }
    asm volatile("s_waitcnt lgkmcnt(0)" ::: "memory");

    // fc4: 4 outputs, split-K over 16-lane groups; q = lane>>4, ks = lane&15
    {
        const int q  = lane >> 4;
        const int ks = lane & 15;
        float4 u = ((const float4*)(fc4w + q * 64))[ks];
        float part = u.x * z3[ks * 4 + 0] + u.y * z3[ks * 4 + 1]
                   + u.z * z3[ks * 4 + 2] + u.w * z3[ks * 4 + 3];
        part += __shfl_xor(part, 1);
        part += __shfl_xor(part, 2);
        part += __shfl_xor(part, 4);
        part += __shfl_xor(part, 8);
        const float kv = 2.0f / (1.0f + expf(-(part + fc4b[q]))) - 1.0f;
        const float k0 = __shfl(kv, 0);
        const float k1 = __shfl(kv, 16);
        const float k2 = __shfl(kv, 32);
        const float k3 = __shfl(kv, 48);
        if (lane == 0) {
            float ax = -(k0 * sgx + k1 * si.z);
            float ay = -(k2 * sgy + k3 * si.w);
            out[i] = make_float2(ax, ay);
        }
    }
}

extern "C" void kernel_launch(void* const* d_in, const int* in_sizes, int n_in,
                              void* d_out, int out_size, void* d_ws, size_t ws_size,
                              hipStream_t stream) {
    const float* s    = (const float*)d_in[0];
    const float* g    = (const float*)d_in[1];
    const float* c1w  = (const float*)d_in[2];
    const float* c1b  = (const float*)d_in[3];
    const float* c2w  = (const float*)d_in[4];
    const float* c2b  = (const float*)d_in[5];
    const float* fc1w = (const float*)d_in[6];
    const float* fc1b = (const float*)d_in[7];
    const float* fc2w = (const float*)d_in[8];
    const float* fc2b = (const float*)d_in[9];
    const float* fc3w = (const float*)d_in[10];
    const float* fc3b = (const float*)d_in[11];
    const float* fc4w = (const float*)d_in[12];
    const float* fc4b = (const float*)d_in[13];

    float2* out = (float2*)d_out;

    NetworkAction_86131274154571_kernel<<<1024, NTH, 0, stream>>>(
        s, g, c1w, c1b, c2w, c2b, fc1w, fc1b, fc2w, fc2b,
        fc3w, fc3b, fc4w, fc4b, out);
}

// Round 3
// 99.861 us; speedup vs baseline: 1.0577x; 1.0454x over previous
//
#include <hip/hip_runtime.h>

typedef unsigned int u32;
typedef unsigned short u16;
typedef _Float16 f16;
typedef f16 f16x8 __attribute__((ext_vector_type(8)));
typedef float f32x4 __attribute__((ext_vector_type(4)));

#define NTH 256
#define SH1 72   // h1 row stride in f16 (144 B = 9*16 B: 16B-aligned frags, no 128B bank wrap)

// Round-0 backbone (best measured: shared compaction, conv1 split over all 256
// threads, conv2 B-frags persistent in VGPRs, 2 N-tiles/wave, 24 KB LDS ->
// 6 blocks/CU residency) with three serialization fixes:
//  1. h1buf double-buffered -> ONE barrier per conv group (was two). Safe
//     because __syncthreads drains lgkmcnt before s_barrier for every wave.
//  2. MLP head on wave 0 only with in-wave s_waitcnt (no block barriers);
//     waves 1-3 retire at the pooling barrier.
//  3. Scan stores (si-sj) diffs + diag slot; conv1 skips re-subtraction.
// Block barriers: ~15 -> 6.
__global__ __launch_bounds__(NTH) void NetworkAction_86131274154571_kernel(
    const float* __restrict__ s,    const float* __restrict__ g,
    const float* __restrict__ w1g,  const float* __restrict__ b1g,
    const float* __restrict__ w2g,  const float* __restrict__ b2g,
    const float* __restrict__ fc1w, const float* __restrict__ fc1b,
    const float* __restrict__ fc2w, const float* __restrict__ fc2b,
    const float* __restrict__ fc3w, const float* __restrict__ fc3b,
    const float* __restrict__ fc4w, const float* __restrict__ fc4b,
    float2* __restrict__ out)
{
    __shared__ float4 actx[1024];        // (dx,dy,dz,dw) = si - sj for actives
    __shared__ f16    h1buf[2][16][SH1]; // double-buffered conv1 tile
    __shared__ float  w1s[320];
    __shared__ float  b1s[64];
    __shared__ float  feat[132];
    __shared__ float  z1[64];
    __shared__ float  z2[128];
    __shared__ float  z3[64];
    __shared__ int    cnt;
    __shared__ int    diagslot;

    const int tid  = threadIdx.x;
    const int lane = tid & 63;
    const int wave = tid >> 6;
    const int i    = blockIdx.x;
    const int ncol = lane & 15;
    const int kq   = lane >> 4;          // 0..3

    if (tid == 0) cnt = 0;
    for (int q = tid; q < 320; q += NTH) w1s[q] = w1g[q];
    if (tid < 64) b1s[tid] = b1g[tid];

    const float4 si = ((const float4*)s)[i];   // uniform

    // ---- conv2 B-fragments (persistent in VGPRs): wave owns channels 32w..32w+31 ----
    // B[k][n] = w2[n][k]; lane: n = n_base + tile*16 + ncol, k = kq*8 + j (+ t*32)
    const int n_base = wave * 32;
    f16x8 bfrag[2][2];                   // [tile][kstep]
    float b2r[2];
    #pragma unroll
    for (int tile = 0; tile < 2; ++tile) {
        const int n = n_base + tile * 16 + ncol;
        b2r[tile] = b2g[n];
        #pragma unroll
        for (int t = 0; t < 2; ++t) {
            const float* wp = w2g + n * 64 + t * 32 + kq * 8;
            float4 lo = ((const float4*)wp)[0];
            float4 hi = ((const float4*)wp)[1];
            f16x8 b;
            b[0] = (f16)lo.x; b[1] = (f16)lo.y; b[2] = (f16)lo.z; b[3] = (f16)lo.w;
            b[4] = (f16)hi.x; b[5] = (f16)hi.y; b[6] = (f16)hi.z; b[7] = (f16)hi.w;
            bfrag[tile][t] = b;
        }
    }
    __syncthreads();   // barrier 1: cnt=0 + w1s/b1s visible

    // ---- Phase 1: scan + compact (per-thread atomicAdd is wave-coalesced by HW) ----
    #pragma unroll
    for (int p = 0; p < 4; ++p) {
        const int j = p * NTH + tid;               // coalesced
        float4 sj = ((const float4*)s)[j];
        float dx = si.x - sj.x, dy = si.y - sj.y;
        if (dx * dx + dy * dy < 0.25f) {
            int slot = atomicAdd(&cnt, 1);
            actx[slot] = make_float4(dx, dy, si.z - sj.z, si.w - sj.w);
            if (j == i) diagslot = slot;           // exactly one writer
        }
    }
    __syncthreads();   // barrier 2
    const int n_act = cnt;                          // >=1 (diagonal)
    const int dslot = diagslot;

    float mtile[2] = {0.0f, 0.0f};

    // ---- Phase 2: groups of 16 pairs, ONE barrier per group (double buffer) ----
    for (int gbase = 0; gbase < n_act; gbase += 16) {
        const int bufI = (gbase >> 4) & 1;
        // conv1: 16 pairs x 32 channel-pairs = 512 items over 256 threads
        #pragma unroll
        for (int it = 0; it < 2; ++it) {
            const int idx = it * NTH + tid;
            const int p = idx >> 5, c2 = idx & 31;
            if (gbase + p < n_act) {
                const float4 x  = actx[gbase + p];
                const float  x4 = (gbase + p == dslot) ? 1.0f : 0.0f;
                const int c = c2 * 2;
                const float* wa = &w1s[c * 5];
                float ha = b1s[c];
                ha = fmaf(wa[0], x.x, ha); ha = fmaf(wa[1], x.y, ha);
                ha = fmaf(wa[2], x.z, ha); ha = fmaf(wa[3], x.w, ha);
                ha = fmaf(wa[4], x4,  ha);
                const float* wb = &w1s[c * 5 + 5];
                float hb = b1s[c + 1];
                hb = fmaf(wb[0], x.x, hb); hb = fmaf(wb[1], x.y, hb);
                hb = fmaf(wb[2], x.z, hb); hb = fmaf(wb[3], x.w, hb);
                hb = fmaf(wb[4], x4,  hb);
                f16 fa = (f16)fmaxf(ha, 0.0f);
                f16 fb = (f16)fmaxf(hb, 0.0f);
                u32 pk = (u32)__builtin_bit_cast(u16, fa) |
                         ((u32)__builtin_bit_cast(u16, fb) << 16);
                *(u32*)&h1buf[bufI][p][c2 * 2] = pk;  // 4B-aligned, 2-way banks (free)
            }
        }
        __syncthreads();   // writes of buf bufI visible; prior reads of bufI^1 drained

        // conv2 MFMA: A-frags shared by both tiles
        f16x8 afr0 = *(const f16x8*)&h1buf[bufI][ncol][kq * 8];        // 16B-aligned
        f16x8 afr1 = *(const f16x8*)&h1buf[bufI][ncol][32 + kq * 8];

        #pragma unroll
        for (int tile = 0; tile < 2; ++tile) {
            f32x4 acc = {0.0f, 0.0f, 0.0f, 0.0f};
            acc = __builtin_amdgcn_mfma_f32_16x16x32_f16(afr0, bfrag[tile][0], acc, 0, 0, 0);
            acc = __builtin_amdgcn_mfma_f32_16x16x32_f16(afr1, bfrag[tile][1], acc, 0, 0, 0);
            // D: pair row = kq*4 + r, channel col = ncol; mask pad rows
            #pragma unroll
            for (int r = 0; r < 4; ++r) {
                const bool valid = (gbase + kq * 4 + r) < n_act;
                const float v = acc[r] + b2r[tile];
                mtile[tile] = valid ? fmaxf(mtile[tile], v) : mtile[tile];
            }
        }
        // no second barrier: next group writes the OTHER buffer
    }

    // reduce across the 4 row-quads holding the same channel column
    #pragma unroll
    for (int tile = 0; tile < 2; ++tile) {
        float m = mtile[tile];
        m = fmaxf(m, __shfl_xor(m, 16));
        m = fmaxf(m, __shfl_xor(m, 32));
        if (lane < 16) feat[n_base + tile * 16 + lane] = m;
    }
    const float2 gi = ((const float2*)g)[i];
    const float sgx = si.x - gi.x, sgy = si.y - gi.y;
    if (tid == 0) {
        feat[128] = sgx; feat[129] = sgy; feat[130] = si.z; feat[131] = si.w;
    }
    __syncthreads();   // barrier: feat complete
    if (wave != 0) return;   // waves 1-3 retire; head is wave-0-only

    // ---- wave-0 head: in-wave s_waitcnt ordering only (validated round 2) ----
    // fc1: out = lane, K=132
    {
        float a0 = fc1b[lane], a1 = 0.f, a2 = 0.f, a3 = 0.f;
        const float4* wv = (const float4*)(fc1w + lane * 132);
        #pragma unroll
        for (int q = 0; q < 33; ++q) {
            float4 u = wv[q];
            const int k = q * 4;
            float* a = (q & 3) == 0 ? &a0 : (q & 3) == 1 ? &a1 : (q & 3) == 2 ? &a2 : &a3;
            *a = fmaf(u.x, feat[k + 0], *a);
            *a = fmaf(u.y, feat[k + 1], *a);
            *a = fmaf(u.z, feat[k + 2], *a);
            *a = fmaf(u.w, feat[k + 3], *a);
        }
        z1[lane] = fmaxf((a0 + a1) + (a2 + a3), 0.0f);
    }
    asm volatile("s_waitcnt lgkmcnt(0)" ::: "memory");

    // fc2: out = lane and lane+64, K=64
    {
        float aA0 = fc2b[lane],      aA1 = 0.f;
        float aB0 = fc2b[lane + 64], aB1 = 0.f;
        const float4* wvA = (const float4*)(fc2w + lane * 64);
        const float4* wvB = (const float4*)(fc2w + (lane + 64) * 64);
        #pragma unroll
        for (int q = 0; q < 16; ++q) {
            float4 uA = wvA[q];
            float4 uB = wvB[q];
            const int k = q * 4;
            const float f0 = z1[k + 0], f1 = z1[k + 1], f2 = z1[k + 2], f3 = z1[k + 3];
            if (q & 1) {
                aA1 = fmaf(uA.x, f0, aA1); aA1 = fmaf(uA.y, f1, aA1);
                aA1 = fmaf(uA.z, f2, aA1); aA1 = fmaf(uA.w, f3, aA1);
                aB1 = fmaf(uB.x, f0, aB1); aB1 = fmaf(uB.y, f1, aB1);
                aB1 = fmaf(uB.z, f2, aB1); aB1 = fmaf(uB.w, f3, aB1);
            } else {
                aA0 = fmaf(uA.x, f0, aA0); aA0 = fmaf(uA.y, f1, aA0);
                aA0 = fmaf(uA.z, f2, aA0); aA0 = fmaf(uA.w, f3, aA0);
                aB0 = fmaf(uB.x, f0, aB0); aB0 = fmaf(uB.y, f1, aB0);
                aB0 = fmaf(uB.z, f2, aB0); aB0 = fmaf(uB.w, f3, aB0);
            }
        }
        z2[lane]      = fmaxf(aA0 + aA1, 0.0f);
        z2[lane + 64] = fmaxf(aB0 + aB1, 0.0f);
    }
    asm volatile("s_waitcnt lgkmcnt(0)" ::: "memory");

    // fc3: out = lane, K=128
    {
        float a0 = fc3b[lane], a1 = 0.f, a2 = 0.f, a3 = 0.f;
        const float4* wv = (const float4*)(fc3w + lane * 128);
        #pragma unroll
        for (int q = 0; q < 32; ++q) {
            float4 u = wv[q];
            const int k = q * 4;
            float* a = (q & 3) == 0 ? &a0 : (q & 3) == 1 ? &a1 : (q & 3) == 2 ? &a2 : &a3;
            *a = fmaf(u.x, z2[k + 0], *a);
            *a = fmaf(u.y, z2[k + 1], *a);
            *a = fmaf(u.z, z2[k + 2], *a);
            *a = fmaf(u.w, z2[k + 3], *a);
        }
        z3[lane] = fmaxf((a0 + a1) + (a2 + a3), 0.0f);
    }
    asm volatile("s_waitcnt lgkmcnt(0)" ::: "memory");

    // fc4: 4 outputs, split-K over 16-lane groups; q = lane>>4, ks = lane&15
    {
        const int q  = lane >> 4;
        const int ks = lane & 15;
        float4 u = ((const float4*)(fc4w + q * 64))[ks];
        float part = u.x * z3[ks * 4 + 0] + u.y * z3[ks * 4 + 1]
                   + u.z * z3[ks * 4 + 2] + u.w * z3[ks * 4 + 3];
        part += __shfl_xor(part, 1);
        part += __shfl_xor(part, 2);
        part += __shfl_xor(part, 4);
        part += __shfl_xor(part, 8);
        const float kv = 2.0f / (1.0f + expf(-(part + fc4b[q]))) - 1.0f;
        const float k0 = __shfl(kv, 0);
        const float k1 = __shfl(kv, 16);
        const float k2 = __shfl(kv, 32);
        const float k3 = __shfl(kv, 48);
        if (lane == 0) {
            float ax = -(k0 * sgx + k1 * si.z);
            float ay = -(k2 * sgy + k3 * si.w);
            out[i] = make_float2(ax, ay);
        }
    }
}

extern "C" void kernel_launch(void* const* d_in, const int* in_sizes, int n_in,
                              void* d_out, int out_size, void* d_ws, size_t ws_size,
                              hipStream_t stream) {
    const float* s    = (const float*)d_in[0];
    const float* g    = (const float*)d_in[1];
    const float* c1w  = (const float*)d_in[2];
    const float* c1b  = (const float*)d_in[3];
    const float* c2w  = (const float*)d_in[4];
    const float* c2b  = (const float*)d_in[5];
    const float* fc1w = (const float*)d_in[6];
    const float* fc1b = (const float*)d_in[7];
    const float* fc2w = (const float*)d_in[8];
    const float* fc2b = (const float*)d_in[9];
    const float* fc3w = (const float*)d_in[10];
    const float* fc3b = (const float*)d_in[11];
    const float* fc4w = (const float*)d_in[12];
    const float* fc4b = (const float*)d_in[13];

    float2* out = (float2*)d_out;

    NetworkAction_86131274154571_kernel<<<1024, NTH, 0, stream>>>(
        s, g, c1w, c1b, c2w, c2b, fc1w, fc1b, fc2w, fc2b,
        fc3w, fc3b, fc4w, fc4b, out);
}